// Round 11
// baseline (1112.425 us; speedup 1.0000x reference)
//
#include <hip/hip_runtime.h>

#define NN 100000
#define NE 1600000
#define NG 4096
#define HID 128
#define ODIM 64
#define BN_EPS 1e-5f
#define NBUK 782    // ceil(NN/128) buckets of 128 nodes
#define BPAD 896    // max padding per bucket (128 nodes * 7)
#define CHUNK 16384 // edges per scatter block
#define PREP_HIST 256
#define PREP_GOFF 17  // ceil((NG+1)/256)
#define PREP_W 192    // 3 * 128*128 / 256

typedef unsigned int u32;
typedef unsigned short u16;
typedef short short8 __attribute__((ext_vector_type(8)));
typedef float f32x4 __attribute__((ext_vector_type(4)));

// bf16 pack (RNE) of two floats -> uint (lo = a, hi = b)
__device__ inline u32 pack_bf16(float a, float b) {
  u32 ua = __float_as_uint(a), ub = __float_as_uint(b);
  ua += 0x7fffu + ((ua >> 16) & 1u);
  ub += 0x7fffu + ((ub >> 16) & 1u);
  return (ua >> 16) | (ub & 0xffff0000u);
}
__device__ inline u16 bf16_of(float v) {
  u32 ua = __float_as_uint(v);
  ua += 0x7fffu + ((ua >> 16) & 1u);
  return (u16)(ua >> 16);
}
__device__ inline float bf_lo(u32 u) { return __uint_as_float(u << 16); }
__device__ inline float bf_hi(u32 u) { return __uint_as_float(u & 0xffff0000u); }

// ---------------- fused prep: bucket histogram + graph offsets + 3x weight transpose ----------------
__global__ __launch_bounds__(256) void k_prep(const int* __restrict__ ei, int* __restrict__ bcnt,
                                              const int* __restrict__ batch, int* __restrict__ goff,
                                              const float* __restrict__ W1, const float* __restrict__ W2,
                                              const float* __restrict__ W3, u16* __restrict__ Wt1,
                                              u16* __restrict__ Wt2, u16* __restrict__ Wt3) {
  __shared__ int h[NBUK];
  int b = blockIdx.x, t = threadIdx.x;
  if (b < PREP_HIST) {
    for (int i = t; i < NBUK; i += 256) h[i] = 0;
    __syncthreads();
    const int stride = PREP_HIST * 256;
    for (int e = b * 256 + t; e < NE; e += stride)
      atomicAdd(&h[ei[NE + e] >> 7], 1);
    __syncthreads();
    for (int i = t; i < NBUK; i += 256)
      if (h[i]) atomicAdd(&bcnt[i], h[i]);
  } else if (b < PREP_HIST + PREP_GOFF) {
    int g = (b - PREP_HIST) * 256 + t;
    if (g <= NG) {
      int lo = 0, hi = NN;
      while (lo < hi) { int mid = (lo + hi) >> 1; if (batch[mid] < g) lo = mid + 1; else hi = mid; }
      goff[g] = lo;
    }
  } else {
    int idx = (b - PREP_HIST - PREP_GOFF) * 256 + t;  // 0..49151
    int mat = idx >> 14;
    int rem = idx & 16383;
    int n = rem >> 7, k = rem & 127;
    const float* W = (mat == 0) ? W1 : (mat == 1) ? W2 : W3;
    u16* Wt = (mat == 0) ? Wt1 : (mat == 1) ? Wt2 : Wt3;
    Wt[(n << 7) + k] = bf16_of(W[(k << 7) + n]);
  }
}

// ---------------- scan bucket counts -> bucket offsets + cursors ----------------
__global__ __launch_bounds__(1024) void k_bscan(const int* __restrict__ bcnt, int* __restrict__ bboff,
                                                int* __restrict__ bcur, int* __restrict__ off) {
  __shared__ int ls[1024];
  int t = threadIdx.x;
  ls[t] = (t < NBUK) ? bcnt[t] : 0;
  __syncthreads();
  for (int d = 1; d < 1024; d <<= 1) {
    int v = 0;
    if (t >= d) v = ls[t - d];
    __syncthreads();
    ls[t] += v;
    __syncthreads();
  }
  if (t < NBUK) {
    int ex = (t == 0) ? 0 : ls[t - 1];
    bboff[t] = ex;
    bcur[t] = ex;
  }
  if (t == 0) { bboff[NBUK] = NE; off[NN] = NE + BPAD * NBUK; }  // padded total
}

// ---------------- scatter edges into bucket-major buffer, LDS-aggregated atomics ----------------
__global__ __launch_bounds__(1024) void k_bscatter(const int* __restrict__ ei, int* __restrict__ bcur,
                                                   u32* __restrict__ ebuf) {
  __shared__ int cnt[NBUK], rnk[NBUK], base[NBUK];
  int t = threadIdx.x;
  int e0 = blockIdx.x * CHUNK;
  for (int i = t; i < NBUK; i += 1024) { cnt[i] = 0; rnk[i] = 0; }
  __syncthreads();
  for (int i = t; i < CHUNK; i += 1024) {
    int e = e0 + i;
    if (e < NE) atomicAdd(&cnt[ei[NE + e] >> 7], 1);
  }
  __syncthreads();
  for (int i = t; i < NBUK; i += 1024) {
    int c = cnt[i];
    base[i] = c ? atomicAdd(&bcur[i], c) : 0;
  }
  __syncthreads();
  for (int i = t; i < CHUNK; i += 1024) {
    int e = e0 + i;
    if (e < NE) {
      int s = ei[e], d = ei[NE + e];
      int b = d >> 7;
      int r = atomicAdd(&rnk[b], 1);
      ebuf[base[b] + r] = ((u32)(d & 127) << 17) | (u32)s;
    }
  }
}

// ---------------- per-bucket CSR build with per-node pad-to-8 (dummy src = NN -> zero row) ----------------
__global__ __launch_bounds__(256) void k_csr(const u32* __restrict__ ebuf, const int* __restrict__ bboff,
                                             int* __restrict__ off, float* __restrict__ dinv,
                                             u32* __restrict__ csrc) {
  __shared__ int cnt[128], scn[128], cur[128];
  __shared__ int stot;
  int b = blockIdx.x, t = threadIdx.x;
  int n0 = b << 7;
  int ebeg = bboff[b], eend = bboff[b + 1];
  int pboff = ebeg + BPAD * b;  // padded bucket base in csrc
  if (t < 128) cnt[t] = 0;
  __syncthreads();
  for (int e = ebeg + t; e < eend; e += 256) atomicAdd(&cnt[ebuf[e] >> 17], 1);
  __syncthreads();
  int pc = 0;
  if (t < 128) { pc = (cnt[t] + 7) & ~7; scn[t] = pc; }
  __syncthreads();
  for (int d = 1; d < 128; d <<= 1) {
    int v = 0;
    if (t >= d && t < 128) v = scn[t - d];
    __syncthreads();
    if (t < 128) scn[t] += v;
    __syncthreads();
  }
  int nvalid = min(128, NN - n0);
  if (t < 128) {
    int ex = scn[t] - pc;  // exclusive padded offset
    cur[t] = ex;           // real-edge cursor
    if (t < nvalid) {
      off[n0 + t] = pboff + ex;
      dinv[n0 + t] = rsqrtf((float)cnt[t] + 1.0f);
    }
    if (t == 127) stot = scn[127];
  }
  __syncthreads();
  // scatter real edges into padded layout
  for (int e = ebeg + t; e < eend; e += 256) {
    u32 p = ebuf[e];
    int d = p >> 17;
    int pos = pboff + atomicAdd(&cur[d], 1);
    csrc[pos] = p & 0x1ffffu;
  }
  // per-node padding (disjoint from real positions; no sync needed)
  if (t < 128) {
    int ex = scn[t] - pc;
    for (int i = cnt[t]; i < pc; ++i) csrc[pboff + ex + i] = NN;
  }
  // bucket tail gap fill (stot synced by the barrier above)
  int cap = (eend - ebeg) + BPAD;
  for (int i = stot + t; i < cap; i += 256) csrc[pboff + i] = NN;
}

// ---------------- MFMA GEMM (layer 1): A fp32, no BN. h2[r] = dinv[r]*(A[r]@W) ----------------
__global__ __launch_bounds__(256) void k_gemm1(const float* __restrict__ A, const u16* __restrict__ Wt,
                                               const float* __restrict__ dinv, u16* __restrict__ H) {
  __shared__ u16 Ct[128][128];
  u16 (*At)[32] = (u16 (*)[32])(&Ct[0][0]);
  u16 (*Bt)[32] = (u16 (*)[32])(&Ct[32][0]);

  int t = threadIdx.x;
  int w = t >> 6, l = t & 63;
  int quad = l >> 4, lid = l & 15;
  int row0 = blockIdx.x * 128;

  f32x4 acc[2][8];
#pragma unroll
  for (int mt = 0; mt < 2; ++mt)
#pragma unroll
    for (int nt = 0; nt < 8; ++nt) acc[mt][nt] = (f32x4){0.f, 0.f, 0.f, 0.f};

  int ar = t >> 1;
  int ac = (t & 1) << 4;
  int grow = row0 + ar;
  bool aok = grow < NN;

  for (int k0 = 0; k0 < HID; k0 += 32) {
    float4 f0 = {0, 0, 0, 0}, f1 = {0, 0, 0, 0}, f2 = {0, 0, 0, 0}, f3 = {0, 0, 0, 0};
    if (aok) {
      const float4* ap = (const float4*)(A + (size_t)grow * HID + k0 + ac);
      f0 = ap[0]; f1 = ap[1]; f2 = ap[2]; f3 = ap[3];
    }
    uint4 q0, q1;
    q0.x = pack_bf16(f0.x, f0.y); q0.y = pack_bf16(f0.z, f0.w);
    q0.z = pack_bf16(f1.x, f1.y); q0.w = pack_bf16(f1.z, f1.w);
    q1.x = pack_bf16(f2.x, f2.y); q1.y = pack_bf16(f2.z, f2.w);
    q1.z = pack_bf16(f3.x, f3.y); q1.w = pack_bf16(f3.z, f3.w);
    *(uint4*)&At[ar][ac] = q0;
    *(uint4*)&At[ar][ac + 8] = q1;
    const u16* wp = Wt + (size_t)(t >> 1) * HID + k0 + ac;
    *(uint4*)&Bt[t >> 1][ac]     = ((const uint4*)wp)[0];
    *(uint4*)&Bt[t >> 1][ac + 8] = ((const uint4*)wp)[1];
    __syncthreads();
    short8 a0 = *(const short8*)&At[(w << 5) + lid][quad << 3];
    short8 a1 = *(const short8*)&At[(w << 5) + 16 + lid][quad << 3];
#pragma unroll
    for (int nt = 0; nt < 8; ++nt) {
      short8 b = *(const short8*)&Bt[(nt << 4) + lid][quad << 3];
      acc[0][nt] = __builtin_amdgcn_mfma_f32_16x16x32_bf16(a0, b, acc[0][nt], 0, 0, 0);
      acc[1][nt] = __builtin_amdgcn_mfma_f32_16x16x32_bf16(a1, b, acc[1][nt], 0, 0, 0);
    }
    __syncthreads();
  }

  int valid = min(128, NN - row0);
#pragma unroll
  for (int mt = 0; mt < 2; ++mt) {
#pragma unroll
    for (int r = 0; r < 4; ++r) {
      int rl = (w << 5) + (mt << 4) + (quad << 2) + r;
      float dv = (rl < valid) ? dinv[row0 + rl] : 0.f;
#pragma unroll
      for (int nt = 0; nt < 8; ++nt) {
        Ct[rl][(nt << 4) + lid] = bf16_of(acc[mt][nt][r] * dv);
      }
    }
  }
  __syncthreads();
  u16* Hb = H + (size_t)row0 * HID;
  int tot = valid << 4;
  for (int idx = t; idx < tot; idx += 256) {
    ((uint4*)Hb)[idx] = ((const uint4*)Ct)[idx];
  }
}

// BN+ReLU on a bf16 pair
__device__ inline u32 bn_pair(u32 v, float2 sc, float2 sh) {
  float a = fmaxf(fmaf(bf_lo(v), sc.x, sh.x), 0.f);
  float b = fmaxf(fmaf(bf_hi(v), sc.y, sh.y), 0.f);
  return pack_bf16(a, b);
}

// ---------------- MFMA GEMM (layers 2/3): A bf16, BN affine inline from raw sums ----------------
__global__ __launch_bounds__(256) void k_gemm_b(const u16* __restrict__ A, const u16* __restrict__ Wt,
                                                const float* __restrict__ sums, const float* __restrict__ g,
                                                const float* __restrict__ be,
                                                const float* __restrict__ dinv, u16* __restrict__ H) {
  __shared__ u16 Ct[128][128];
  u16 (*At)[32] = (u16 (*)[32])(&Ct[0][0]);   // rows 0..31
  u16 (*Bt)[32] = (u16 (*)[32])(&Ct[32][0]);  // rows 32..63
  float* scsh = (float*)&Ct[64][0];           // rows 64..67, free during K-loop

  int t = threadIdx.x;
  int w = t >> 6, l = t & 63;
  int quad = l >> 4, lid = l & 15;
  int row0 = blockIdx.x * 128;

  if (t < 128) {  // inline bnfinal
    const float invN = 1.0f / (float)NN;
    float mu = sums[t] * invN;
    float var = sums[HID + t] * invN - mu * mu;
    float sc = g[t] * rsqrtf(var + BN_EPS);
    scsh[t] = sc;
    scsh[128 + t] = be[t] - mu * sc;
  }

  f32x4 acc[2][8];
#pragma unroll
  for (int mt = 0; mt < 2; ++mt)
#pragma unroll
    for (int nt = 0; nt < 8; ++nt) acc[mt][nt] = (f32x4){0.f, 0.f, 0.f, 0.f};

  int ar = t >> 1;
  int ac = (t & 1) << 4;
  int grow = row0 + ar;
  bool aok = grow < NN;
  __syncthreads();  // scsh visible

  for (int k0 = 0; k0 < HID; k0 += 32) {
    uint4 q0 = {0, 0, 0, 0}, q1 = {0, 0, 0, 0};
    if (aok) {
      const uint4* ap = (const uint4*)(A + (size_t)grow * HID + k0 + ac);
      q0 = ap[0]; q1 = ap[1];
    }
    const float2* scp = (const float2*)(scsh + k0 + ac);
    const float2* shp = (const float2*)(scsh + 128 + k0 + ac);
    q0.x = bn_pair(q0.x, scp[0], shp[0]); q0.y = bn_pair(q0.y, scp[1], shp[1]);
    q0.z = bn_pair(q0.z, scp[2], shp[2]); q0.w = bn_pair(q0.w, scp[3], shp[3]);
    q1.x = bn_pair(q1.x, scp[4], shp[4]); q1.y = bn_pair(q1.y, scp[5], shp[5]);
    q1.z = bn_pair(q1.z, scp[6], shp[6]); q1.w = bn_pair(q1.w, scp[7], shp[7]);
    *(uint4*)&At[ar][ac] = q0;
    *(uint4*)&At[ar][ac + 8] = q1;
    const u16* wp = Wt + (size_t)(t >> 1) * HID + k0 + ac;
    *(uint4*)&Bt[t >> 1][ac]     = ((const uint4*)wp)[0];
    *(uint4*)&Bt[t >> 1][ac + 8] = ((const uint4*)wp)[1];
    __syncthreads();
    short8 a0 = *(const short8*)&At[(w << 5) + lid][quad << 3];
    short8 a1 = *(const short8*)&At[(w << 5) + 16 + lid][quad << 3];
#pragma unroll
    for (int nt = 0; nt < 8; ++nt) {
      short8 b = *(const short8*)&Bt[(nt << 4) + lid][quad << 3];
      acc[0][nt] = __builtin_amdgcn_mfma_f32_16x16x32_bf16(a0, b, acc[0][nt], 0, 0, 0);
      acc[1][nt] = __builtin_amdgcn_mfma_f32_16x16x32_bf16(a1, b, acc[1][nt], 0, 0, 0);
    }
    __syncthreads();
  }

  int valid = min(128, NN - row0);
#pragma unroll
  for (int mt = 0; mt < 2; ++mt) {
#pragma unroll
    for (int r = 0; r < 4; ++r) {
      int rl = (w << 5) + (mt << 4) + (quad << 2) + r;
      float dv = (rl < valid) ? dinv[row0 + rl] : 0.f;
#pragma unroll
      for (int nt = 0; nt < 8; ++nt) {
        Ct[rl][(nt << 4) + lid] = bf16_of(acc[mt][nt][r] * dv);
      }
    }
  }
  __syncthreads();
  u16* Hb = H + (size_t)row0 * HID;
  int tot = valid << 4;
  for (int idx = t; idx < tot; idx += 256) {
    ((uint4*)Hb)[idx] = ((const uint4*)Ct)[idx];
  }
}

// ---------------- pull aggregation: wave = node, padded lists -> pipelined unroll-8 always ----------------
__global__ __launch_bounds__(256) void k_agg(const u16* __restrict__ h2, const int* __restrict__ off,
                                             const u32* __restrict__ csrc, const float* __restrict__ dinv,
                                             u16* __restrict__ aggb) {
  int node = (int)((blockIdx.x * 256 + threadIdx.x) >> 6);
  int lane = threadIdx.x & 63;
  if (node >= NN) return;
  int beg = off[node], end = off[node + 1];
  u32 us = ((const u32*)(h2 + (size_t)node * HID))[lane];
  float ax = bf_lo(us), ay = bf_hi(us);
  int e = beg;
  for (; e + 8 <= end; e += 8) {
    u32 s[8], v[8];
#pragma unroll
    for (int i = 0; i < 8; ++i) s[i] = csrc[e + i];
#pragma unroll
    for (int i = 0; i < 8; ++i) v[i] = ((const u32*)(h2 + (size_t)s[i] * HID))[lane];
#pragma unroll
    for (int i = 0; i < 8; ++i) { ax += bf_lo(v[i]); ay += bf_hi(v[i]); }
  }
  for (; e < end; ++e) {  // only the last node of a bucket can land here
    u32 v = ((const u32*)(h2 + (size_t)csrc[e] * HID))[lane];
    ax += bf_lo(v);
    ay += bf_hi(v);
  }
  float di = dinv[node];
  ((u32*)(aggb + (size_t)node * HID))[lane] = pack_bf16(ax * di, ay * di);
}

// ---------------- BN statistics over bf16 agg (raw sums into buf) ----------------
__global__ __launch_bounds__(256) void k_bnstats(const u16* __restrict__ X, float* __restrict__ buf) {
  __shared__ float lsx[256], lssx[256], lsy[256], lssy[256];
  int t = threadIdx.x;
  int colp = t & 63, grp = t >> 6;
  int rbeg = blockIdx.x * 256, rend = min(rbeg + 256, NN);
  float sx = 0.f, ssx = 0.f, sy = 0.f, ssy = 0.f;
  for (int r = rbeg + grp; r < rend; r += 4) {
    u32 v = ((const u32*)(X + (size_t)r * HID))[colp];
    float a = bf_lo(v), b = bf_hi(v);
    sx += a; ssx = fmaf(a, a, ssx);
    sy += b; ssy = fmaf(b, b, ssy);
  }
  lsx[t] = sx; lssx[t] = ssx; lsy[t] = sy; lssy[t] = ssy;
  __syncthreads();
  if (t < 64) {
    sx = lsx[t] + lsx[t + 64] + lsx[t + 128] + lsx[t + 192];
    ssx = lssx[t] + lssx[t + 64] + lssx[t + 128] + lssx[t + 192];
    sy = lsy[t] + lsy[t + 64] + lsy[t + 128] + lsy[t + 192];
    ssy = lssy[t] + lssy[t + 64] + lssy[t + 128] + lssy[t + 192];
    atomicAdd(&buf[2 * colp], sx);
    atomicAdd(&buf[2 * colp + 1], sy);
    atomicAdd(&buf[HID + 2 * colp], ssx);
    atomicAdd(&buf[HID + 2 * colp + 1], ssy);
  }
}

// ---------------- fused mean-pool (inline BN+ReLU from raw sums) + FC ----------------
__global__ __launch_bounds__(256) void k_poolfc(const u16* __restrict__ aggb, const float* __restrict__ sums,
                                                const float* __restrict__ g3, const float* __restrict__ be3,
                                                const int* __restrict__ goff, const float* __restrict__ fcW,
                                                const float* __restrict__ fcb, float* __restrict__ out) {
  __shared__ float ls[4][128];
  int t = threadIdx.x;
  int w = t >> 6, lane = t & 63;
  int gr = blockIdx.x * 4 + w;  // grid = NG/4 exactly
  const float invN = 1.0f / (float)NN;
  int f0 = lane << 1, f1 = f0 + 1;
  float mu0 = sums[f0] * invN, mu1 = sums[f1] * invN;
  float v0 = sums[HID + f0] * invN - mu0 * mu0;
  float v1 = sums[HID + f1] * invN - mu1 * mu1;
  float sc0 = g3[f0] * rsqrtf(v0 + BN_EPS), sc1 = g3[f1] * rsqrtf(v1 + BN_EPS);
  float sh0 = be3[f0] - mu0 * sc0, sh1 = be3[f1] - mu1 * sc1;
  int beg = goff[gr], end = goff[gr + 1];
  float ax = 0.f, ay = 0.f;
  for (int r = beg; r < end; ++r) {
    u32 v = ((const u32*)(aggb + (size_t)r * HID))[lane];
    ax += fmaxf(fmaf(bf_lo(v), sc0, sh0), 0.f);
    ay += fmaxf(fmaf(bf_hi(v), sc1, sh1), 0.f);
  }
  float inv = 1.0f / fmaxf((float)(end - beg), 1.0f);
  ls[w][f0] = ax * inv;
  ls[w][f1] = ay * inv;
  __syncthreads();
  float acc = fcb[lane];
#pragma unroll 8
  for (int k = 0; k < HID; ++k) acc = fmaf(ls[w][k], fcW[(size_t)k * ODIM + lane], acc);
  out[(size_t)gr * ODIM + lane] = acc;
}

extern "C" void kernel_launch(void* const* d_in, const int* in_sizes, int n_in,
                              void* d_out, int out_size, void* d_ws, size_t ws_size,
                              hipStream_t stream) {
  const float* x     = (const float*)d_in[0];
  const int*   ei    = (const int*)d_in[1];
  const int*   batch = (const int*)d_in[2];
  const float* W1    = (const float*)d_in[3];
  // b1/b2/b3 (d_in[4,8,12]) skipped: per-feature bias cancels exactly in the following BN
  const float* g1    = (const float*)d_in[5];
  const float* be1   = (const float*)d_in[6];
  const float* W2    = (const float*)d_in[7];
  const float* g2    = (const float*)d_in[9];
  const float* be2   = (const float*)d_in[10];
  const float* W3    = (const float*)d_in[11];
  const float* g3    = (const float*)d_in[13];
  const float* be3   = (const float*)d_in[14];
  const float* fcW   = (const float*)d_in[15];
  const float* fcb   = (const float*)d_in[16];
  float* out = (float*)d_out;

  char* p = (char*)d_ws;
  auto alloc = [&](size_t bytes) { char* r = p; p += (bytes + 255) & ~(size_t)255; return r; };
  int*   bcnt   = (int*)alloc((size_t)NBUK * 4);
  float* bnb    = (float*)alloc(3 * 256 * 4);
  size_t zbytes = (size_t)(p - (char*)d_ws);
  int*   bboff  = (int*)alloc((size_t)(NBUK + 1) * 4);
  int*   bcur   = (int*)alloc((size_t)NBUK * 4);
  int*   off    = (int*)alloc((size_t)(NN + 1) * 4);
  float* dinv   = (float*)alloc((size_t)NN * 4);
  u32*   ebuf   = (u32*)alloc((size_t)NE * 4);
  u32*   csrc   = (u32*)alloc(((size_t)NE + (size_t)BPAD * NBUK) * 4);
  int*   goff   = (int*)alloc((size_t)(NG + 1) * 4);
  u16*   Wt1    = (u16*)alloc((size_t)HID * HID * 2);
  u16*   Wt2    = (u16*)alloc((size_t)HID * HID * 2);
  u16*   Wt3    = (u16*)alloc((size_t)HID * HID * 2);
  u16*   h2     = (u16*)alloc((size_t)(NN + 1) * HID * 2);  // +1 zero row for dummy edges
  u16*   aggb   = (u16*)alloc((size_t)NN * HID * 2);

  hipMemsetAsync(d_ws, 0, zbytes, stream);
  hipMemsetAsync(h2 + (size_t)NN * HID, 0, HID * 2, stream);  // zero row for padding gathers

  const int NB = (NN + 255) / 256;          // 391
  const int GB = (NN + 127) / 128;          // 782 gemm blocks
  const int AGB = NN / 4;                   // 25000 agg blocks (4 waves = 4 nodes each)
  const int SB = (NE + CHUNK - 1) / CHUNK;  // 98 scatter blocks

  k_prep<<<PREP_HIST + PREP_GOFF + PREP_W, 256, 0, stream>>>(ei, bcnt, batch, goff, W1, W2, W3, Wt1, Wt2, Wt3);
  k_bscan<<<1, 1024, 0, stream>>>(bcnt, bboff, bcur, off);
  k_bscatter<<<SB, 1024, 0, stream>>>(ei, bcur, ebuf);
  k_csr<<<NBUK, 256, 0, stream>>>(ebuf, bboff, off, dinv, csrc);

  // layer 1
  k_gemm1<<<GB, 256, 0, stream>>>(x, Wt1, dinv, h2);
  k_agg<<<AGB, 256, 0, stream>>>(h2, off, csrc, dinv, aggb);
  k_bnstats<<<NB, 256, 0, stream>>>(aggb, bnb);
  // layer 2 (BN affine from layer-1 sums computed inline in gemm)
  k_gemm_b<<<GB, 256, 0, stream>>>(aggb, Wt2, bnb, g1, be1, dinv, h2);
  k_agg<<<AGB, 256, 0, stream>>>(h2, off, csrc, dinv, aggb);
  k_bnstats<<<NB, 256, 0, stream>>>(aggb, bnb + 256);
  // layer 3
  k_gemm_b<<<GB, 256, 0, stream>>>(aggb, Wt3, bnb + 256, g2, be2, dinv, h2);
  k_agg<<<AGB, 256, 0, stream>>>(h2, off, csrc, dinv, aggb);
  k_bnstats<<<NB, 256, 0, stream>>>(aggb, bnb + 512);
  // pool + BN + FC fused
  k_poolfc<<<NG / 4, 256, 0, stream>>>(aggb, bnb + 512, g3, be3, goff, fcW, fcb, out);
}

// Round 12
// 525.119 us; speedup vs baseline: 2.1184x; 2.1184x over previous
//
#include <hip/hip_runtime.h>

#define NN 100000
#define NE 1600000
#define NG 4096
#define HID 128
#define ODIM 64
#define BN_EPS 1e-5f
#define NBUK 782    // ceil(NN/128) buckets of 128 nodes
#define BPAD 896    // max padding per bucket (128 nodes * 7)
#define NZROW 256   // distinct zero rows for dummy gathers (avoid hot-line)
#define CHUNK 16384 // edges per scatter block
#define PREP_HIST 256
#define PREP_GOFF 17  // ceil((NG+1)/256)
#define PREP_W 192    // 3 * 128*128 / 256

typedef unsigned int u32;
typedef unsigned short u16;
typedef short short8 __attribute__((ext_vector_type(8)));
typedef float f32x4 __attribute__((ext_vector_type(4)));

// bf16 pack (RNE) of two floats -> uint (lo = a, hi = b)
__device__ inline u32 pack_bf16(float a, float b) {
  u32 ua = __float_as_uint(a), ub = __float_as_uint(b);
  ua += 0x7fffu + ((ua >> 16) & 1u);
  ub += 0x7fffu + ((ub >> 16) & 1u);
  return (ua >> 16) | (ub & 0xffff0000u);
}
__device__ inline u16 bf16_of(float v) {
  u32 ua = __float_as_uint(v);
  ua += 0x7fffu + ((ua >> 16) & 1u);
  return (u16)(ua >> 16);
}
__device__ inline float bf_lo(u32 u) { return __uint_as_float(u << 16); }
__device__ inline float bf_hi(u32 u) { return __uint_as_float(u & 0xffff0000u); }

// ---------------- fused prep: bucket histogram + graph offsets + 3x weight transpose ----------------
__global__ __launch_bounds__(256) void k_prep(const int* __restrict__ ei, int* __restrict__ bcnt,
                                              const int* __restrict__ batch, int* __restrict__ goff,
                                              const float* __restrict__ W1, const float* __restrict__ W2,
                                              const float* __restrict__ W3, u16* __restrict__ Wt1,
                                              u16* __restrict__ Wt2, u16* __restrict__ Wt3) {
  __shared__ int h[NBUK];
  int b = blockIdx.x, t = threadIdx.x;
  if (b < PREP_HIST) {
    for (int i = t; i < NBUK; i += 256) h[i] = 0;
    __syncthreads();
    const int stride = PREP_HIST * 256;
    for (int e = b * 256 + t; e < NE; e += stride)
      atomicAdd(&h[ei[NE + e] >> 7], 1);
    __syncthreads();
    for (int i = t; i < NBUK; i += 256)
      if (h[i]) atomicAdd(&bcnt[i], h[i]);
  } else if (b < PREP_HIST + PREP_GOFF) {
    int g = (b - PREP_HIST) * 256 + t;
    if (g <= NG) {
      int lo = 0, hi = NN;
      while (lo < hi) { int mid = (lo + hi) >> 1; if (batch[mid] < g) lo = mid + 1; else hi = mid; }
      goff[g] = lo;
    }
  } else {
    int idx = (b - PREP_HIST - PREP_GOFF) * 256 + t;  // 0..49151
    int mat = idx >> 14;
    int rem = idx & 16383;
    int n = rem >> 7, k = rem & 127;
    const float* W = (mat == 0) ? W1 : (mat == 1) ? W2 : W3;
    u16* Wt = (mat == 0) ? Wt1 : (mat == 1) ? Wt2 : Wt3;
    Wt[(n << 7) + k] = bf16_of(W[(k << 7) + n]);
  }
}

// ---------------- scan bucket counts -> bucket offsets + cursors ----------------
__global__ __launch_bounds__(1024) void k_bscan(const int* __restrict__ bcnt, int* __restrict__ bboff,
                                                int* __restrict__ bcur) {
  __shared__ int ls[1024];
  int t = threadIdx.x;
  ls[t] = (t < NBUK) ? bcnt[t] : 0;
  __syncthreads();
  for (int d = 1; d < 1024; d <<= 1) {
    int v = 0;
    if (t >= d) v = ls[t - d];
    __syncthreads();
    ls[t] += v;
    __syncthreads();
  }
  if (t < NBUK) {
    int ex = (t == 0) ? 0 : ls[t - 1];
    bboff[t] = ex;
    bcur[t] = ex;
  }
  if (t == 0) bboff[NBUK] = NE;
}

// ---------------- scatter edges into bucket-major buffer, LDS-aggregated atomics ----------------
__global__ __launch_bounds__(1024) void k_bscatter(const int* __restrict__ ei, int* __restrict__ bcur,
                                                   u32* __restrict__ ebuf) {
  __shared__ int cnt[NBUK], rnk[NBUK], base[NBUK];
  int t = threadIdx.x;
  int e0 = blockIdx.x * CHUNK;
  for (int i = t; i < NBUK; i += 1024) { cnt[i] = 0; rnk[i] = 0; }
  __syncthreads();
  for (int i = t; i < CHUNK; i += 1024) {
    int e = e0 + i;
    if (e < NE) atomicAdd(&cnt[ei[NE + e] >> 7], 1);
  }
  __syncthreads();
  for (int i = t; i < NBUK; i += 1024) {
    int c = cnt[i];
    base[i] = c ? atomicAdd(&bcur[i], c) : 0;
  }
  __syncthreads();
  for (int i = t; i < CHUNK; i += 1024) {
    int e = e0 + i;
    if (e < NE) {
      int s = ei[e], d = ei[NE + e];
      int b = d >> 7;
      int r = atomicAdd(&rnk[b], 1);
      ebuf[base[b] + r] = ((u32)(d & 127) << 17) | (u32)s;
    }
  }
}

// ---------------- per-bucket CSR build: pad-to-8 per node, explicit end array, spread dummies ----------------
__global__ __launch_bounds__(256) void k_csr(const u32* __restrict__ ebuf, const int* __restrict__ bboff,
                                             int* __restrict__ off, int* __restrict__ oend,
                                             float* __restrict__ dinv, u32* __restrict__ csrc) {
  __shared__ int cnt[128], scn[128], cur[128];
  int b = blockIdx.x, t = threadIdx.x;
  int n0 = b << 7;
  int ebeg = bboff[b], eend = bboff[b + 1];
  int pboff = ebeg + BPAD * b;  // padded bucket base in csrc
  if (t < 128) cnt[t] = 0;
  __syncthreads();
  for (int e = ebeg + t; e < eend; e += 256) atomicAdd(&cnt[ebuf[e] >> 17], 1);
  __syncthreads();
  int pc = 0;
  if (t < 128) { pc = (cnt[t] + 7) & ~7; scn[t] = pc; }
  __syncthreads();
  for (int d = 1; d < 128; d <<= 1) {
    int v = 0;
    if (t >= d && t < 128) v = scn[t - d];
    __syncthreads();
    if (t < 128) scn[t] += v;
    __syncthreads();
  }
  int nvalid = min(128, NN - n0);
  if (t < 128) {
    int ex = scn[t] - pc;  // exclusive padded offset
    cur[t] = ex;           // real-edge cursor
    if (t < nvalid) {
      off[n0 + t] = pboff + ex;
      oend[n0 + t] = pboff + scn[t];  // end = beg + padded count (never touches the bucket gap)
      dinv[n0 + t] = rsqrtf((float)cnt[t] + 1.0f);
    }
  }
  __syncthreads();
  // scatter real edges into padded layout
  for (int e = ebeg + t; e < eend; e += 256) {
    u32 p = ebuf[e];
    int d = p >> 17;
    int pos = pboff + atomicAdd(&cur[d], 1);
    csrc[pos] = p & 0x1ffffu;
  }
  // per-node padding: dummy srcs spread over NZROW zero rows (disjoint positions; no sync needed)
  if (t < 128) {
    int ex = scn[t] - pc;
    for (int i = cnt[t]; i < pc; ++i)
      csrc[pboff + ex + i] = (u32)(NN + ((n0 + t + i) & (NZROW - 1)));
  }
}

// ---------------- MFMA GEMM (layer 1): A fp32, no BN. h2[r] = dinv[r]*(A[r]@W) ----------------
__global__ __launch_bounds__(256) void k_gemm1(const float* __restrict__ A, const u16* __restrict__ Wt,
                                               const float* __restrict__ dinv, u16* __restrict__ H) {
  __shared__ u16 Ct[128][128];
  u16 (*At)[32] = (u16 (*)[32])(&Ct[0][0]);
  u16 (*Bt)[32] = (u16 (*)[32])(&Ct[32][0]);

  int t = threadIdx.x;
  int w = t >> 6, l = t & 63;
  int quad = l >> 4, lid = l & 15;
  int row0 = blockIdx.x * 128;

  f32x4 acc[2][8];
#pragma unroll
  for (int mt = 0; mt < 2; ++mt)
#pragma unroll
    for (int nt = 0; nt < 8; ++nt) acc[mt][nt] = (f32x4){0.f, 0.f, 0.f, 0.f};

  int ar = t >> 1;
  int ac = (t & 1) << 4;
  int grow = row0 + ar;
  bool aok = grow < NN;

  for (int k0 = 0; k0 < HID; k0 += 32) {
    float4 f0 = {0, 0, 0, 0}, f1 = {0, 0, 0, 0}, f2 = {0, 0, 0, 0}, f3 = {0, 0, 0, 0};
    if (aok) {
      const float4* ap = (const float4*)(A + (size_t)grow * HID + k0 + ac);
      f0 = ap[0]; f1 = ap[1]; f2 = ap[2]; f3 = ap[3];
    }
    uint4 q0, q1;
    q0.x = pack_bf16(f0.x, f0.y); q0.y = pack_bf16(f0.z, f0.w);
    q0.z = pack_bf16(f1.x, f1.y); q0.w = pack_bf16(f1.z, f1.w);
    q1.x = pack_bf16(f2.x, f2.y); q1.y = pack_bf16(f2.z, f2.w);
    q1.z = pack_bf16(f3.x, f3.y); q1.w = pack_bf16(f3.z, f3.w);
    *(uint4*)&At[ar][ac] = q0;
    *(uint4*)&At[ar][ac + 8] = q1;
    const u16* wp = Wt + (size_t)(t >> 1) * HID + k0 + ac;
    *(uint4*)&Bt[t >> 1][ac]     = ((const uint4*)wp)[0];
    *(uint4*)&Bt[t >> 1][ac + 8] = ((const uint4*)wp)[1];
    __syncthreads();
    short8 a0 = *(const short8*)&At[(w << 5) + lid][quad << 3];
    short8 a1 = *(const short8*)&At[(w << 5) + 16 + lid][quad << 3];
#pragma unroll
    for (int nt = 0; nt < 8; ++nt) {
      short8 b = *(const short8*)&Bt[(nt << 4) + lid][quad << 3];
      acc[0][nt] = __builtin_amdgcn_mfma_f32_16x16x32_bf16(a0, b, acc[0][nt], 0, 0, 0);
      acc[1][nt] = __builtin_amdgcn_mfma_f32_16x16x32_bf16(a1, b, acc[1][nt], 0, 0, 0);
    }
    __syncthreads();
  }

  int valid = min(128, NN - row0);
#pragma unroll
  for (int mt = 0; mt < 2; ++mt) {
#pragma unroll
    for (int r = 0; r < 4; ++r) {
      int rl = (w << 5) + (mt << 4) + (quad << 2) + r;
      float dv = (rl < valid) ? dinv[row0 + rl] : 0.f;
#pragma unroll
      for (int nt = 0; nt < 8; ++nt) {
        Ct[rl][(nt << 4) + lid] = bf16_of(acc[mt][nt][r] * dv);
      }
    }
  }
  __syncthreads();
  u16* Hb = H + (size_t)row0 * HID;
  int tot = valid << 4;
  for (int idx = t; idx < tot; idx += 256) {
    ((uint4*)Hb)[idx] = ((const uint4*)Ct)[idx];
  }
}

// BN+ReLU on a bf16 pair
__device__ inline u32 bn_pair(u32 v, float2 sc, float2 sh) {
  float a = fmaxf(fmaf(bf_lo(v), sc.x, sh.x), 0.f);
  float b = fmaxf(fmaf(bf_hi(v), sc.y, sh.y), 0.f);
  return pack_bf16(a, b);
}

// ---------------- MFMA GEMM (layers 2/3): A bf16, BN affine inline from raw sums ----------------
__global__ __launch_bounds__(256) void k_gemm_b(const u16* __restrict__ A, const u16* __restrict__ Wt,
                                                const float* __restrict__ sums, const float* __restrict__ g,
                                                const float* __restrict__ be,
                                                const float* __restrict__ dinv, u16* __restrict__ H) {
  __shared__ u16 Ct[128][128];
  u16 (*At)[32] = (u16 (*)[32])(&Ct[0][0]);   // rows 0..31
  u16 (*Bt)[32] = (u16 (*)[32])(&Ct[32][0]);  // rows 32..63
  float* scsh = (float*)&Ct[64][0];           // rows 64..67, free during K-loop

  int t = threadIdx.x;
  int w = t >> 6, l = t & 63;
  int quad = l >> 4, lid = l & 15;
  int row0 = blockIdx.x * 128;

  if (t < 128) {  // inline bnfinal
    const float invN = 1.0f / (float)NN;
    float mu = sums[t] * invN;
    float var = sums[HID + t] * invN - mu * mu;
    float sc = g[t] * rsqrtf(var + BN_EPS);
    scsh[t] = sc;
    scsh[128 + t] = be[t] - mu * sc;
  }

  f32x4 acc[2][8];
#pragma unroll
  for (int mt = 0; mt < 2; ++mt)
#pragma unroll
    for (int nt = 0; nt < 8; ++nt) acc[mt][nt] = (f32x4){0.f, 0.f, 0.f, 0.f};

  int ar = t >> 1;
  int ac = (t & 1) << 4;
  int grow = row0 + ar;
  bool aok = grow < NN;
  __syncthreads();  // scsh visible

  for (int k0 = 0; k0 < HID; k0 += 32) {
    uint4 q0 = {0, 0, 0, 0}, q1 = {0, 0, 0, 0};
    if (aok) {
      const uint4* ap = (const uint4*)(A + (size_t)grow * HID + k0 + ac);
      q0 = ap[0]; q1 = ap[1];
    }
    const float2* scp = (const float2*)(scsh + k0 + ac);
    const float2* shp = (const float2*)(scsh + 128 + k0 + ac);
    q0.x = bn_pair(q0.x, scp[0], shp[0]); q0.y = bn_pair(q0.y, scp[1], shp[1]);
    q0.z = bn_pair(q0.z, scp[2], shp[2]); q0.w = bn_pair(q0.w, scp[3], shp[3]);
    q1.x = bn_pair(q1.x, scp[4], shp[4]); q1.y = bn_pair(q1.y, scp[5], shp[5]);
    q1.z = bn_pair(q1.z, scp[6], shp[6]); q1.w = bn_pair(q1.w, scp[7], shp[7]);
    *(uint4*)&At[ar][ac] = q0;
    *(uint4*)&At[ar][ac + 8] = q1;
    const u16* wp = Wt + (size_t)(t >> 1) * HID + k0 + ac;
    *(uint4*)&Bt[t >> 1][ac]     = ((const uint4*)wp)[0];
    *(uint4*)&Bt[t >> 1][ac + 8] = ((const uint4*)wp)[1];
    __syncthreads();
    short8 a0 = *(const short8*)&At[(w << 5) + lid][quad << 3];
    short8 a1 = *(const short8*)&At[(w << 5) + 16 + lid][quad << 3];
#pragma unroll
    for (int nt = 0; nt < 8; ++nt) {
      short8 b = *(const short8*)&Bt[(nt << 4) + lid][quad << 3];
      acc[0][nt] = __builtin_amdgcn_mfma_f32_16x16x32_bf16(a0, b, acc[0][nt], 0, 0, 0);
      acc[1][nt] = __builtin_amdgcn_mfma_f32_16x16x32_bf16(a1, b, acc[1][nt], 0, 0, 0);
    }
    __syncthreads();
  }

  int valid = min(128, NN - row0);
#pragma unroll
  for (int mt = 0; mt < 2; ++mt) {
#pragma unroll
    for (int r = 0; r < 4; ++r) {
      int rl = (w << 5) + (mt << 4) + (quad << 2) + r;
      float dv = (rl < valid) ? dinv[row0 + rl] : 0.f;
#pragma unroll
      for (int nt = 0; nt < 8; ++nt) {
        Ct[rl][(nt << 4) + lid] = bf16_of(acc[mt][nt][r] * dv);
      }
    }
  }
  __syncthreads();
  u16* Hb = H + (size_t)row0 * HID;
  int tot = valid << 4;
  for (int idx = t; idx < tot; idx += 256) {
    ((uint4*)Hb)[idx] = ((const uint4*)Ct)[idx];
  }
}

// ---------------- pull aggregation: wave = node, padded lists (multiple of 8) -> always pipelined ----------------
__global__ __launch_bounds__(256) void k_agg(const u16* __restrict__ h2, const int* __restrict__ off,
                                             const int* __restrict__ oend, const u32* __restrict__ csrc,
                                             const float* __restrict__ dinv, u16* __restrict__ aggb) {
  int node = (int)((blockIdx.x * 256 + threadIdx.x) >> 6);
  int lane = threadIdx.x & 63;
  if (node >= NN) return;
  int beg = off[node], end = oend[node];
  u32 us = ((const u32*)(h2 + (size_t)node * HID))[lane];
  float ax = bf_lo(us), ay = bf_hi(us);
  for (int e = beg; e < end; e += 8) {  // end-beg is always a multiple of 8
    u32 s[8], v[8];
#pragma unroll
    for (int i = 0; i < 8; ++i) s[i] = csrc[e + i];
#pragma unroll
    for (int i = 0; i < 8; ++i) v[i] = ((const u32*)(h2 + (size_t)s[i] * HID))[lane];
#pragma unroll
    for (int i = 0; i < 8; ++i) { ax += bf_lo(v[i]); ay += bf_hi(v[i]); }
  }
  float di = dinv[node];
  ((u32*)(aggb + (size_t)node * HID))[lane] = pack_bf16(ax * di, ay * di);
}

// ---------------- BN statistics over bf16 agg (raw sums into buf) ----------------
__global__ __launch_bounds__(256) void k_bnstats(const u16* __restrict__ X, float* __restrict__ buf) {
  __shared__ float lsx[256], lssx[256], lsy[256], lssy[256];
  int t = threadIdx.x;
  int colp = t & 63, grp = t >> 6;
  int rbeg = blockIdx.x * 256, rend = min(rbeg + 256, NN);
  float sx = 0.f, ssx = 0.f, sy = 0.f, ssy = 0.f;
  for (int r = rbeg + grp; r < rend; r += 4) {
    u32 v = ((const u32*)(X + (size_t)r * HID))[colp];
    float a = bf_lo(v), b = bf_hi(v);
    sx += a; ssx = fmaf(a, a, ssx);
    sy += b; ssy = fmaf(b, b, ssy);
  }
  lsx[t] = sx; lssx[t] = ssx; lsy[t] = sy; lssy[t] = ssy;
  __syncthreads();
  if (t < 64) {
    sx = lsx[t] + lsx[t + 64] + lsx[t + 128] + lsx[t + 192];
    ssx = lssx[t] + lssx[t + 64] + lssx[t + 128] + lssx[t + 192];
    sy = lsy[t] + lsy[t + 64] + lsy[t + 128] + lsy[t + 192];
    ssy = lssy[t] + lssy[t + 64] + lssy[t + 128] + lssy[t + 192];
    atomicAdd(&buf[2 * colp], sx);
    atomicAdd(&buf[2 * colp + 1], sy);
    atomicAdd(&buf[HID + 2 * colp], ssx);
    atomicAdd(&buf[HID + 2 * colp + 1], ssy);
  }
}

// ---------------- fused mean-pool (inline BN+ReLU from raw sums) + FC ----------------
__global__ __launch_bounds__(256) void k_poolfc(const u16* __restrict__ aggb, const float* __restrict__ sums,
                                                const float* __restrict__ g3, const float* __restrict__ be3,
                                                const int* __restrict__ goff, const float* __restrict__ fcW,
                                                const float* __restrict__ fcb, float* __restrict__ out) {
  __shared__ float ls[4][128];
  int t = threadIdx.x;
  int w = t >> 6, lane = t & 63;
  int gr = blockIdx.x * 4 + w;  // grid = NG/4 exactly
  const float invN = 1.0f / (float)NN;
  int f0 = lane << 1, f1 = f0 + 1;
  float mu0 = sums[f0] * invN, mu1 = sums[f1] * invN;
  float v0 = sums[HID + f0] * invN - mu0 * mu0;
  float v1 = sums[HID + f1] * invN - mu1 * mu1;
  float sc0 = g3[f0] * rsqrtf(v0 + BN_EPS), sc1 = g3[f1] * rsqrtf(v1 + BN_EPS);
  float sh0 = be3[f0] - mu0 * sc0, sh1 = be3[f1] - mu1 * sc1;
  int beg = goff[gr], end = goff[gr + 1];
  float ax = 0.f, ay = 0.f;
  for (int r = beg; r < end; ++r) {
    u32 v = ((const u32*)(aggb + (size_t)r * HID))[lane];
    ax += fmaxf(fmaf(bf_lo(v), sc0, sh0), 0.f);
    ay += fmaxf(fmaf(bf_hi(v), sc1, sh1), 0.f);
  }
  float inv = 1.0f / fmaxf((float)(end - beg), 1.0f);
  ls[w][f0] = ax * inv;
  ls[w][f1] = ay * inv;
  __syncthreads();
  float acc = fcb[lane];
#pragma unroll 8
  for (int k = 0; k < HID; ++k) acc = fmaf(ls[w][k], fcW[(size_t)k * ODIM + lane], acc);
  out[(size_t)gr * ODIM + lane] = acc;
}

extern "C" void kernel_launch(void* const* d_in, const int* in_sizes, int n_in,
                              void* d_out, int out_size, void* d_ws, size_t ws_size,
                              hipStream_t stream) {
  const float* x     = (const float*)d_in[0];
  const int*   ei    = (const int*)d_in[1];
  const int*   batch = (const int*)d_in[2];
  const float* W1    = (const float*)d_in[3];
  // b1/b2/b3 (d_in[4,8,12]) skipped: per-feature bias cancels exactly in the following BN
  const float* g1    = (const float*)d_in[5];
  const float* be1   = (const float*)d_in[6];
  const float* W2    = (const float*)d_in[7];
  const float* g2    = (const float*)d_in[9];
  const float* be2   = (const float*)d_in[10];
  const float* W3    = (const float*)d_in[11];
  const float* g3    = (const float*)d_in[13];
  const float* be3   = (const float*)d_in[14];
  const float* fcW   = (const float*)d_in[15];
  const float* fcb   = (const float*)d_in[16];
  float* out = (float*)d_out;

  char* p = (char*)d_ws;
  auto alloc = [&](size_t bytes) { char* r = p; p += (bytes + 255) & ~(size_t)255; return r; };
  int*   bcnt   = (int*)alloc((size_t)NBUK * 4);
  float* bnb    = (float*)alloc(3 * 256 * 4);
  size_t zbytes = (size_t)(p - (char*)d_ws);
  int*   bboff  = (int*)alloc((size_t)(NBUK + 1) * 4);
  int*   bcur   = (int*)alloc((size_t)NBUK * 4);
  int*   off    = (int*)alloc((size_t)NN * 4);
  int*   oend   = (int*)alloc((size_t)NN * 4);
  float* dinv   = (float*)alloc((size_t)NN * 4);
  u32*   ebuf   = (u32*)alloc((size_t)NE * 4);
  u32*   csrc   = (u32*)alloc(((size_t)NE + (size_t)BPAD * NBUK) * 4);
  int*   goff   = (int*)alloc((size_t)(NG + 1) * 4);
  u16*   Wt1    = (u16*)alloc((size_t)HID * HID * 2);
  u16*   Wt2    = (u16*)alloc((size_t)HID * HID * 2);
  u16*   Wt3    = (u16*)alloc((size_t)HID * HID * 2);
  u16*   h2     = (u16*)alloc((size_t)(NN + NZROW) * HID * 2);  // + NZROW zero rows for dummies
  u16*   aggb   = (u16*)alloc((size_t)NN * HID * 2);

  hipMemsetAsync(d_ws, 0, zbytes, stream);
  hipMemsetAsync(h2 + (size_t)NN * HID, 0, (size_t)NZROW * HID * 2, stream);  // 64 KB zero rows

  const int NB = (NN + 255) / 256;          // 391
  const int GB = (NN + 127) / 128;          // 782 gemm blocks
  const int AGB = NN / 4;                   // 25000 agg blocks (4 waves = 4 nodes each)
  const int SB = (NE + CHUNK - 1) / CHUNK;  // 98 scatter blocks

  k_prep<<<PREP_HIST + PREP_GOFF + PREP_W, 256, 0, stream>>>(ei, bcnt, batch, goff, W1, W2, W3, Wt1, Wt2, Wt3);
  k_bscan<<<1, 1024, 0, stream>>>(bcnt, bboff, bcur);
  k_bscatter<<<SB, 1024, 0, stream>>>(ei, bcur, ebuf);
  k_csr<<<NBUK, 256, 0, stream>>>(ebuf, bboff, off, oend, dinv, csrc);

  // layer 1
  k_gemm1<<<GB, 256, 0, stream>>>(x, Wt1, dinv, h2);
  k_agg<<<AGB, 256, 0, stream>>>(h2, off, oend, csrc, dinv, aggb);
  k_bnstats<<<NB, 256, 0, stream>>>(aggb, bnb);
  // layer 2 (BN affine from layer-1 sums computed inline in gemm)
  k_gemm_b<<<GB, 256, 0, stream>>>(aggb, Wt2, bnb, g1, be1, dinv, h2);
  k_agg<<<AGB, 256, 0, stream>>>(h2, off, oend, csrc, dinv, aggb);
  k_bnstats<<<NB, 256, 0, stream>>>(aggb, bnb + 256);
  // layer 3
  k_gemm_b<<<GB, 256, 0, stream>>>(aggb, Wt3, bnb + 256, g2, be2, dinv, h2);
  k_agg<<<AGB, 256, 0, stream>>>(h2, off, oend, csrc, dinv, aggb);
  k_bnstats<<<NB, 256, 0, stream>>>(aggb, bnb + 512);
  // pool + BN + FC fused
  k_poolfc<<<NG / 4, 256, 0, stream>>>(aggb, bnb + 512, g3, be3, goff, fcW, fcb, out);
}